// Round 1
// baseline (14.190 us; speedup 1.0000x reference)
//
#include <hip/hip_runtime.h>
#include <hip/hip_bf16.h>

// Problem constants (B=2, H=8, S=256, d=64) from setup_inputs().
#define B_ 2
#define H_ 8
#define S_ 256
#define D_ 64
#define ROWS (B_ * H_ * S_)          // 4096
#define PER_B (H_ * S_ * D_)         // 131072
#define GZ_P 512                     // zero-padded p axis
#define GZ_PER_B (GZ_P * D_)         // 32768
#define OUT_HALF (B_ * H_ * S_ * D_) // 262144

// Scratch for zero-padded group sums G[b][p][e], p in [0,512), e in [0,64).
// Module-scope device memory: safe under graph capture, no ws_size assumption.
__device__ float g_Gz[B_ * GZ_PER_B];

// K1: G[b,p,e] = sum_{t0<8} Q[b, p>>5, (p&31)*8+t0, e] * V[same]  (p<256), else 0.
__global__ __launch_bounds__(256) void k_groupsum(const float* __restrict__ Q,
                                                  const float* __restrict__ V) {
    int tid = blockIdx.x * 256 + threadIdx.x;   // 65536 threads total
    int e = tid & 63;
    int p = (tid >> 6) & 511;
    int b = tid >> 15;
    float acc = 0.0f;
    if (p < 256) {
        int hp = p >> 5;
        int sbase = (p & 31) << 3;
        const float* q = Q + (size_t)b * PER_B + hp * (S_ * D_) + sbase * D_ + e;
        const float* v = V + (size_t)b * PER_B + hp * (S_ * D_) + sbase * D_ + e;
#pragma unroll
        for (int t0 = 0; t0 < 8; ++t0)
            acc += q[t0 * D_] * v[t0 * D_];
    }
    g_Gz[tid] = acc;   // tid == b*32768 + p*64 + e
}

// K2: one 64-lane wave per (b,h,s) row; lane = e.
// scores[e] = sum_{t1<64} Gz[b][(base0+t1)&511][e]; softmax over e; ctx = attn*V.
__global__ __launch_bounds__(256) void k_attn(const float* __restrict__ V,
                                              float* __restrict__ out) {
    int lane = threadIdx.x & 63;                   // e
    int wave = threadIdx.x >> 6;
    int row = blockIdx.x * 4 + wave;               // 0..4095
    int b = row >> 11;
    int h = (row >> 8) & 7;
    int s = row & 255;

    const float* g = g_Gz + b * GZ_PER_B;
    int base0 = ((s & 7) << 6) + (h << 5) + (s >> 3) + 256;

    float score = 0.0f;
#pragma unroll
    for (int t1 = 0; t1 < 64; ++t1)
        score += g[((base0 + t1) & 511) * D_ + lane];

    // softmax across the 64-lane wave (axis = d)
    float m = score;
#pragma unroll
    for (int off = 32; off > 0; off >>= 1)
        m = fmaxf(m, __shfl_xor(m, off));
    float ex = expf(score - m);
    float sum = ex;
#pragma unroll
    for (int off = 32; off > 0; off >>= 1)
        sum += __shfl_xor(sum, off);

    float attn = ex / sum;
    float ctx = attn * V[row * D_ + lane];

    out[row * D_ + lane] = ctx;                    // context, output 0
    out[OUT_HALF + row * D_ + lane] = attn;        // attn,    output 1
}

extern "C" void kernel_launch(void* const* d_in, const int* in_sizes, int n_in,
                              void* d_out, int out_size, void* d_ws, size_t ws_size,
                              hipStream_t stream) {
    const float* Q = (const float*)d_in[0];
    // d_in[1] (K) is unused by the reference.
    const float* V = (const float*)d_in[2];
    float* out = (float*)d_out;

    // K1: 2*512*64 = 65536 threads
    k_groupsum<<<(B_ * GZ_PER_B) / 256, 256, 0, stream>>>(Q, V);
    // K2: 4096 rows, 4 waves (256 threads) per block
    k_attn<<<ROWS / 4, 256, 0, stream>>>(V, out);
}

// Round 2
// 12.053 us; speedup vs baseline: 1.1773x; 1.1773x over previous
//
#include <hip/hip_runtime.h>
#include <hip/hip_bf16.h>

// Problem constants (B=2, H=8, S=256, d=64) from setup_inputs().
#define B_ 2
#define H_ 8
#define S_ 256
#define D_ 64
#define PER_B (H_ * S_ * D_)         // 131072
#define OUT_HALF (B_ * H_ * S_ * D_) // 262144
#define NROWS 95                     // 32 (k span) + 63 (window tail)

// Derivation (verified by the passing round-0 kernel):
//   G[b,p,e] = sum_{t0<8} Q[b, p>>5, (p&31)*8+t0, e] * V[same],  p<256; 0 else
//   score[b,h,s,e] = sum_{t1<64} Gz[b][(base0+t1)&511][e],
//       base0 = (s&7)*64 + 32h + (s>>3) + 256
//   softmax over e; context = attn * V.
// Fused form: block = (b, h, m=s&7). Its 32 rows (k = s>>3 in [0,32)) need
// G rows p = (P0 + j) & 511 for j in [0,95), P0 = 64m + 32h + 256.

__global__ __launch_bounds__(512) void k_fused(const float* __restrict__ Q,
                                               const float* __restrict__ V,
                                               float* __restrict__ out) {
    __shared__ float Gl[NROWS][D_];   // 24320 B
    const int lane = threadIdx.x & 63;   // e
    const int wave = threadIdx.x >> 6;   // 0..7
    const int bid = blockIdx.x;          // 0..127
    const int m = bid & 7;
    const int h = (bid >> 3) & 7;
    const int b = bid >> 6;
    const int P0 = (m << 6) + (h << 5) + 256;

    // ---- Phase 1: build the 95 needed G rows in LDS ----
    const float* Qb = Q + b * PER_B;
    const float* Vb = V + b * PER_B;
    for (int j = wave; j < NROWS; j += 8) {
        int p = (P0 + j) & 511;
        float acc = 0.0f;
        if (p < 256) {
            int off = (p >> 5) * (S_ * D_) + ((p & 31) << 3) * D_ + lane;
#pragma unroll
            for (int t0 = 0; t0 < 8; ++t0)
                acc += Qb[off + t0 * D_] * Vb[off + t0 * D_];
        }
        Gl[j][lane] = acc;
    }
    __syncthreads();

    // ---- Phase 2: wave handles k = 4*wave .. 4*wave+3 via sliding window ----
    const int k0 = wave << 2;
    float score = 0.0f;
#pragma unroll
    for (int t1 = 0; t1 < 64; ++t1)
        score += Gl[k0 + t1][lane];

#pragma unroll
    for (int kk = 0; kk < 4; ++kk) {
        int k = k0 + kk;
        int s = (k << 3) + m;

        // softmax across the 64-lane wave (axis = d)
        float mx = score;
#pragma unroll
        for (int off = 32; off > 0; off >>= 1)
            mx = fmaxf(mx, __shfl_xor(mx, off));
        float ex = __expf(score - mx);
        float sum = ex;
#pragma unroll
        for (int off = 32; off > 0; off >>= 1)
            sum += __shfl_xor(sum, off);

        float attn = ex / sum;
        int row = (b * H_ + h) * S_ + s;
        float v = V[row * D_ + lane];
        out[row * D_ + lane] = attn * v;             // context (output 0)
        out[OUT_HALF + row * D_ + lane] = attn;      // attn    (output 1)

        if (kk < 3)
            score += Gl[k + 64][lane] - Gl[k][lane]; // slide window by 1
    }
}

extern "C" void kernel_launch(void* const* d_in, const int* in_sizes, int n_in,
                              void* d_out, int out_size, void* d_ws, size_t ws_size,
                              hipStream_t stream) {
    const float* Q = (const float*)d_in[0];
    // d_in[1] (K) is unused by the reference.
    const float* V = (const float*)d_in[2];
    float* out = (float*)d_out;

    k_fused<<<B_ * H_ * 8, 512, 0, stream>>>(Q, V, out);  // 128 blocks
}

// Round 3
// 10.748 us; speedup vs baseline: 1.3203x; 1.1214x over previous
//
#include <hip/hip_runtime.h>
#include <hip/hip_bf16.h>

// Problem constants (B=2, H=8, S=256, d=64) from setup_inputs().
#define B_ 2
#define H_ 8
#define S_ 256
#define D_ 64
#define PER_B (H_ * S_ * D_)         // 131072
#define OUT_HALF (B_ * H_ * S_ * D_) // 262144
#define NR 96                        // padded G rows in LDS (need 95)
#define NQ 24                        // quad-sum rows (NR/4)

// Derivation (verified by passing round-0/1 kernels):
//   G[b,p,e] = sum_{t0<8} Q[b, p>>5, (p&31)*8+t0, e] * V[same],  p<256; 0 else
//   score[b,h,s,e] = sum_{t1<64} Gz[b][(base0+t1)&511][e],
//       base0 = (s&7)*64 + 32h + (s>>3) + 256
//   softmax over e; context = attn * V.
// Block = (b, h, m=s&7); rows k = s>>3 in [0,32) need G rows
// p = (P0 + j) & 511 for j in [0,95), P0 = 64m + 32h + 256.
// Key layout fact: the 8x64 Q (and V) sub-block feeding one G row is 512
// CONTIGUOUS floats -> float4 loads, lane owns an e-quad, 4 rows per wave.

__global__ __launch_bounds__(512) void k_fused(const float* __restrict__ Q,
                                               const float* __restrict__ V,
                                               float* __restrict__ out) {
    __shared__ float Gl[NR][D_];   // 24 KiB
    __shared__ float Q4[NQ][D_];   // 6 KiB  (quad sums of Gl rows)
    const int lane = threadIdx.x & 63;
    const int wave = threadIdx.x >> 6;   // 0..7
    const int bid = blockIdx.x;          // 0..127
    const int m = bid & 7;
    const int h = (bid >> 3) & 7;
    const int b = bid >> 6;
    const int P0 = (m << 6) + (h << 5) + 256;

    const float* Qb = Q + b * PER_B;
    const float* Vb = V + b * PER_B;

    // ---- Phase 1: build 96 G rows, 4 rows per wave-iteration, float4 loads ----
    const int sub = lane >> 4;           // which of the 4 rows in the group
    const int ec  = (lane & 15) << 2;    // e-quad base (0,4,...,60)
#pragma unroll
    for (int g = wave; g < NQ; g += 8) { // groups w, w+8, w+16
        int j = (g << 2) + sub;
        int p = (P0 + j) & 511;
        float4 acc = {0.f, 0.f, 0.f, 0.f};
        if (p < 256) {
            int off = (p >> 5) * (S_ * D_) + ((p & 31) << 3) * D_ + ec;
            const float* qp = Qb + off;
            const float* vp = Vb + off;
#pragma unroll
            for (int t0 = 0; t0 < 8; ++t0) {
                float4 q4 = *(const float4*)(qp + t0 * D_);
                float4 v4 = *(const float4*)(vp + t0 * D_);
                acc.x += q4.x * v4.x;
                acc.y += q4.y * v4.y;
                acc.z += q4.z * v4.z;
                acc.w += q4.w * v4.w;
            }
        }
        *(float4*)(&Gl[j][ec]) = acc;
    }
    __syncthreads();

    // ---- Phase 2a: quad sums Q4[q] = Gl[4q]+Gl[4q+1]+Gl[4q+2]+Gl[4q+3] ----
#pragma unroll
    for (int q = wave; q < NQ; q += 8)
        Q4[q][lane] = Gl[4 * q][lane] + Gl[4 * q + 1][lane] +
                      Gl[4 * q + 2][lane] + Gl[4 * q + 3][lane];
    __syncthreads();

    // ---- Phase 2b: wave w -> k = 4w..4w+3, quad-aligned initial window ----
    const int k0 = wave << 2;
    float score = 0.0f;
#pragma unroll
    for (int t = 0; t < 16; ++t)         // window [4w,4w+64) = quads w..w+15
        score += Q4[wave + t][lane];

#pragma unroll
    for (int kk = 0; kk < 4; ++kk) {
        int k = k0 + kk;
        int s = (k << 3) + m;

        float mx = score;
#pragma unroll
        for (int off = 32; off > 0; off >>= 1)
            mx = fmaxf(mx, __shfl_xor(mx, off));
        float ex = __expf(score - mx);
        float sum = ex;
#pragma unroll
        for (int off = 32; off > 0; off >>= 1)
            sum += __shfl_xor(sum, off);

        float attn = ex / sum;
        int row = (b * H_ + h) * S_ + s;
        float v = V[row * D_ + lane];
        out[row * D_ + lane] = attn * v;             // context (output 0)
        out[OUT_HALF + row * D_ + lane] = attn;      // attn    (output 1)

        if (kk < 3)
            score += Gl[k + 64][lane] - Gl[k][lane]; // slide window by 1
    }
}

extern "C" void kernel_launch(void* const* d_in, const int* in_sizes, int n_in,
                              void* d_out, int out_size, void* d_ws, size_t ws_size,
                              hipStream_t stream) {
    const float* Q = (const float*)d_in[0];
    // d_in[1] (K) is unused by the reference.
    const float* V = (const float*)d_in[2];
    float* out = (float*)d_out;

    k_fused<<<B_ * H_ * 8, 512, 0, stream>>>(Q, V, out);  // 128 blocks
}

// Round 4
// 9.675 us; speedup vs baseline: 1.4667x; 1.1109x over previous
//
#include <hip/hip_runtime.h>
#include <hip/hip_bf16.h>

// Problem constants (B=2, H=8, S=256, d=64) from setup_inputs().
#define B_ 2
#define H_ 8
#define S_ 256
#define D_ 64
#define PER_B (H_ * S_ * D_)         // 131072
#define OUT_HALF (B_ * H_ * S_ * D_) // 262144
#define NR 80                        // G rows staged per block (need 79)
#define NQ 20                        // quad-sum rows (NR/4)

// Derivation (verified by passing round-0..3 kernels):
//   G[b,p,e] = sum_{t0<8} Q[b, p>>5, (p&31)*8+t0, e] * V[same],  p<256; 0 else
//   score[b,h,s,e] = sum_{t1<64} Gz[b][(base0+t1)&511][e],
//       base0 = (s&7)*64 + 32h + (s>>3) + 256
//   softmax over e; context = attn * V.
// Block = (b, h, m=s&7, half): rows k = 16*half + kl, kl in [0,16), need
// local G rows jl in [0,79), p = (P0 + jl) & 511, P0 = 64m + 32h + 256 + 16*half.
// The 8x64 Q/V sub-block per G row is 512 CONTIGUOUS floats -> float4 loads.

__global__ __launch_bounds__(512) void k_fused(const float* __restrict__ Q,
                                               const float* __restrict__ V,
                                               float* __restrict__ out) {
    __shared__ float Gl[NR][D_];   // 20 KiB
    __shared__ float Q4[NQ][D_];   // 5 KiB (aligned quad sums of Gl)
    const int lane = threadIdx.x & 63;
    const int wave = threadIdx.x >> 6;    // 0..7
    const int bid  = blockIdx.x;          // 0..255
    const int half = bid & 1;
    const int m    = (bid >> 1) & 7;
    const int h    = (bid >> 4) & 7;
    const int b    = bid >> 7;
    const int P0   = (m << 6) + (h << 5) + 256 + (half << 4);

    const float* Qb = Q + b * PER_B;
    const float* Vb = V + b * PER_B;

    // ---- Phase 1: build 80 G rows (4/wave-iter, float4 loads) + quad sums ----
    const int sub = lane >> 4;            // row within the quad group
    const int ec  = (lane & 15) << 2;     // e-quad base
#pragma unroll
    for (int g = wave; g < NQ; g += 8) {  // waves 0..3: 3 groups, 4..7: 2
        int j = (g << 2) + sub;
        int p = (P0 + j) & 511;
        float4 acc = {0.f, 0.f, 0.f, 0.f};
        if (p < 256) {
            int off = (p >> 5) * (S_ * D_) + ((p & 31) << 3) * D_ + ec;
            const float* qp = Qb + off;
            const float* vp = Vb + off;
#pragma unroll
            for (int t0 = 0; t0 < 8; ++t0) {
                float4 q4 = *(const float4*)(qp + t0 * D_);
                float4 v4 = *(const float4*)(vp + t0 * D_);
                acc.x += q4.x * v4.x;
                acc.y += q4.y * v4.y;
                acc.z += q4.z * v4.z;
                acc.w += q4.w * v4.w;
            }
        }
        *(float4*)(&Gl[j][ec]) = acc;

        // quad sum across the 4 sub-rows via shuffles (no extra LDS pass)
        float4 a2, a4;
        a2.x = acc.x + __shfl_xor(acc.x, 16);
        a2.y = acc.y + __shfl_xor(acc.y, 16);
        a2.z = acc.z + __shfl_xor(acc.z, 16);
        a2.w = acc.w + __shfl_xor(acc.w, 16);
        a4.x = a2.x + __shfl_xor(a2.x, 32);
        a4.y = a2.y + __shfl_xor(a2.y, 32);
        a4.z = a2.z + __shfl_xor(a2.z, 32);
        a4.w = a2.w + __shfl_xor(a2.w, 32);
        if (sub == 0)
            *(float4*)(&Q4[g][ec]) = a4;
    }
    __syncthreads();

    // ---- Phase 2: wave w -> kl = 2w, 2w+1 (sliding window) ----
    const int kl0 = wave << 1;
    float score = 0.0f;
    if ((wave & 1) == 0) {
        // kl0 % 4 == 0: window = quads kl0/4 .. kl0/4+15
        int q0 = kl0 >> 2;
#pragma unroll
        for (int t = 0; t < 16; ++t)
            score += Q4[q0 + t][lane];
    } else {
        // kl0 % 4 == 2: 2 leading rows + 15 quads + 2 trailing rows
        score = Gl[kl0][lane] + Gl[kl0 + 1][lane] +
                Gl[kl0 + 62][lane] + Gl[kl0 + 63][lane];
        int q0 = (kl0 + 2) >> 2;
#pragma unroll
        for (int t = 0; t < 15; ++t)
            score += Q4[q0 + t][lane];
    }

#pragma unroll
    for (int kk = 0; kk < 2; ++kk) {
        int kl = kl0 + kk;
        int s = (((half << 4) + kl) << 3) + m;
        int row = (b * H_ + h) * S_ + s;
        float v = V[row * D_ + lane];   // issue early; hides under shuffles

        float mx = score;
#pragma unroll
        for (int off = 32; off > 0; off >>= 1)
            mx = fmaxf(mx, __shfl_xor(mx, off));
        float ex = __expf(score - mx);
        float sum = ex;
#pragma unroll
        for (int off = 32; off > 0; off >>= 1)
            sum += __shfl_xor(sum, off);

        float attn = ex / sum;
        out[row * D_ + lane] = attn * v;             // context (output 0)
        out[OUT_HALF + row * D_ + lane] = attn;      // attn    (output 1)

        if (kk == 0)
            score += Gl[kl + 64][lane] - Gl[kl][lane]; // slide window
    }
}

extern "C" void kernel_launch(void* const* d_in, const int* in_sizes, int n_in,
                              void* d_out, int out_size, void* d_ws, size_t ws_size,
                              hipStream_t stream) {
    const float* Q = (const float*)d_in[0];
    // d_in[1] (K) is unused by the reference.
    const float* V = (const float*)d_in[2];
    float* out = (float*)d_out;

    k_fused<<<B_ * H_ * 8 * 2, 512, 0, stream>>>(Q, V, out);  // 256 blocks
}